// Round 12
// baseline (14264.069 us; speedup 1.0000x reference)
//
#include <hip/hip_runtime.h>
#include <stdint.h>

#define NN 4096
#define VD 8192
#define NE 65536
#define NSTEPS 100
#define CSR_CAP 98304  // 65536 + worst-case per-node pad (<= 7*4096) rounded up

#define GWG 8          // GNN workgroups (active bids 0,8,...,56 of a 64-block launch)
#define SSTR 448       // flag ints per step: 7 layers x 64 per-wave flags
#define BARN (NSTEPS * SSTR)

// ---------- helpers ----------
__device__ __forceinline__ uint32_t f2bf(float f) {
    uint32_t x = __float_as_uint(f);
    return (x + 0x7FFFu + ((x >> 16) & 1u)) >> 16;
}
__device__ __forceinline__ float bfl(uint32_t w) { return __uint_as_float(w << 16); }
__device__ __forceinline__ float bfh(uint32_t w) { return __uint_as_float(w & 0xFFFF0000u); }

__device__ __forceinline__ void flag_set(int* f) {
    // release: waits this WAVE's outstanding stores (vmcnt is per-wave), then publishes
    __hip_atomic_store(f, 1, __ATOMIC_RELEASE, __HIP_MEMORY_SCOPE_AGENT);
}

// ---------- setup kernels ----------
__global__ void k_zero(int* deg, int* fill, float* v0, uint32_t* csrw, int* bar) {
    int t = blockIdx.x * 256 + threadIdx.x;           // grid covers 49152
    if (t < 4096) { deg[t] = 0; fill[t] = 0; }
    if (t < 8192) v0[t] = 0.f;
    if (t < BARN) bar[t] = 0;                         // monotonic flags, zeroed per replay
    if (t < CSR_CAP / 2) csrw[t] = 0x10001000u;       // sentinel src = 4096
}

__global__ void k_deg(const int* ei, int* deg) {
    int e = blockIdx.x * 256 + threadIdx.x;
    if (e < NE) atomicAdd(&deg[ei[NE + e]], 1);
}

__global__ __launch_bounds__(1024) void k_scan(const int* deg, int* pad_ptr, float* dinv) {
    __shared__ int sh[1024];
    int t = threadIdx.x;
    int d[4], pl[4], tsum = 0;
    for (int j = 0; j < 4; ++j) {
        d[j] = deg[t * 4 + j];
        pl[j] = (d[j] + 7) & ~7;
        tsum += pl[j];
    }
    sh[t] = tsum;
    __syncthreads();
    for (int off = 1; off < 1024; off <<= 1) {
        int v = sh[t];
        if (t >= off) v += sh[t - off];
        __syncthreads();
        sh[t] = v;
        __syncthreads();
    }
    int base = sh[t] - tsum;  // exclusive prefix
    for (int j = 0; j < 4; ++j) {
        pad_ptr[t * 4 + j] = base;
        base += pl[j];
        dinv[t * 4 + j] = rsqrtf((float)(d[j] + 1));  // +1 self loop, always > 0
    }
    if (t == 0) dinv[4096] = 0.f;  // sentinel
}

__global__ void k_fill(const int* ei, const int* pad_ptr, int* fill, uint16_t* csr) {
    int e = blockIdx.x * 256 + threadIdx.x;
    if (e < NE) {
        int s = ei[e];
        int d = ei[NE + e];
        int pos = atomicAdd(&fill[d], 1);
        csr[pad_ptr[d] + pos] = (uint16_t)s;
    }
}

__global__ void k_r(const int* deg, const int* pad_ptr, const uint16_t* csr,
                    const float* dinv, float* rr) {
    int n = blockIdx.x * 256 + threadIdx.x;
    if (n >= NN) return;
    float dv = dinv[n];
    int base = pad_ptr[n];
    int nch = (deg[n] + 7) >> 3;
    float sum = 0.f;
    for (int c = 0; c < nch; ++c)
        for (int k = 0; k < 8; ++k) sum += dinv[csr[base + c * 8 + k]];  // sentinel adds 0
    rr[n] = dv * sum + dv * dv;
}

__global__ void k_m(const float* A, const float* B, const float* bw, float* m) {
    int t = blockIdx.x * 256 + threadIdx.x;  // 65536
    if (t >= VD * 8) return;
    int i = t >> 3, k = t & 7;
    m[t] = A[(size_t)i * 8200 + 8192 + k] + B[(size_t)i * 8200 + 8192 + k] + bw[i * 8 + k];
}

// per-step layer-0 constants, precomputed once (hoisted out of k_gnn's prologue)
__global__ void k_c(const float* W0, const float* b0, const float* gse, float* cbuf) {
    int s = blockIdx.x * 64 + threadIdx.x;
    if (s >= NSTEPS) return;
    const float* gs = gse + 8 * s;
    float c0_0 = b0[0] + b0[2], c0_1 = b0[1] + b0[3];
    float c1_0 = 0.f, c1_1 = 0.f;
    for (int k = 0; k < 8; ++k) {
        float sv = gs[k];
        c0_0 += sv * W0[(2 + k) * 2 + 0];
        c0_1 += sv * W0[(2 + k) * 2 + 1];
        c1_0 += sv * W0[20 + (2 + k) * 2 + 0];
        c1_1 += sv * W0[20 + (2 + k) * 2 + 1];
    }
    ((float4*)cbuf)[s] = make_float4(c0_0, c0_1, c1_0, c1_1);
}

__global__ __launch_bounds__(256) void k_az(const float* A, const float* z, float* az) {
    int wave = threadIdx.x >> 6, lane = threadIdx.x & 63;
    int r = blockIdx.x * 4 + wave;
    const float* row = A + (size_t)r * 8200;
    float acc = 0.f;
    for (int j = 0; j < 32; ++j) {
        int c = j * 256 + lane * 4;
        float4 a = *(const float4*)(row + c);
        float4 zz = *(const float4*)(z + c);
        acc += a.x * zz.x + a.y * zz.y + a.z * zz.z + a.w * zz.w;
    }
    for (int o = 32; o; o >>= 1) acc += __shfl_down(acc, o);
    if (lane == 0) az[r] = acc;
}

// Permuted B16 layout: row r, uint4 index p = jj*64 + l holds bf16 of cols
// {jj*512+4l .. +3} (words x,y) and {jj*512+256+4l .. +3} (words z,w).
// This makes the mv-phase su reads contiguous 16B/lane -> conflict-free LDS.
__global__ __launch_bounds__(256) void k_bconv(const float* B, uint16_t* B16) {
    int t = blockIdx.x * 256 + threadIdx.x;  // VD*1024 threads, one uint4 each
    int i = t >> 10;
    int p = t & 1023;
    int jj = p >> 6, l = p & 63;
    const float* pr = B + (size_t)i * 8200 + jj * 512 + l * 4;
    float4 a = *(const float4*)pr;
    float4 b = *(const float4*)(pr + 256);
    uint4 w;
    w.x = f2bf(a.x) | (f2bf(a.y) << 16);
    w.y = f2bf(a.z) | (f2bf(a.w) << 16);
    w.z = f2bf(b.x) | (f2bf(b.y) << 16);
    w.w = f2bf(b.z) | (f2bf(b.w) << 16);
    ((uint4*)B16)[t] = w;
}

// ---------- per-step GNN: 8 WGs, double-buffered LDS y, per-wave flag exchange ----------
#define GATH(W) { float2 yy0 = ycur[(W) & 0xFFFFu]; a0 += yy0.x; a1 += yy0.y; \
                  float2 yy1 = ycur[(W) >> 16];     a0 += yy1.x; a1 += yy1.y; }

__global__ __launch_bounds__(512) void k_gnn(
    const float* __restrict__ vin, float* __restrict__ us,
    float2* __restrict__ ybuf, int* __restrict__ sb,
    const uint16_t* __restrict__ csr, const int* __restrict__ pad_ptr,
    const int* __restrict__ deg, const float* __restrict__ dinv,
    const float* __restrict__ rr,
    const float* __restrict__ W0, const float* __restrict__ b0,
    const float* __restrict__ Wh, const float* __restrict__ bh,
    const float* __restrict__ cst) {
    const int bid = blockIdx.x;
    if (bid & 7) return;                 // active: 0,8,..,56 -> one XCD under bid%8 round-robin
    __shared__ float2 ybb[2][NN + 1];    // double buffer; [*][4096] = 0 sentinel
    const int g = bid >> 3;              // 0..7
    const int t = threadIdx.x;           // 0..511
    const int n = g * 512 + t;

    const float dv = dinv[n], rv = rr[n], dv2 = dv * dv;
    const int base = pad_ptr[n];
    const int nch = (deg[n] + 7) >> 3;
    const uint16_t* cp = csr + base;
    float dmy[8];
    #pragma unroll
    for (int j = 0; j < 8; ++j) dmy[j] = dinv[j * 512 + t];

    const float4 cc = *(const float4*)cst;   // precomputed layer-0 step constants

    float2* ycur = ybb[0];
    float2* ynxt = ybb[1];

    float x0 = vin[n], x1 = vin[n + NN];
    #pragma unroll
    for (int j = 0; j < 8; ++j) {
        int mm = j * 512 + t;
        ycur[mm] = make_float2(vin[mm] * dmy[j], vin[mm + NN] * dmy[j]);
    }
    if (t == 0) {
        ybb[0][NN] = make_float2(0.f, 0.f);
        ybb[1][NN] = make_float2(0.f, 0.f);
    }
    __syncthreads();

    for (int l = 0; l < 8; ++l) {
        float wa00, wa01, wa10, wa11, wb00, wb01, wb10, wb11, bb0, bb1, e0, e1;
        if (l == 0) {
            wa00 = W0[0]; wa01 = W0[1]; wa10 = W0[2]; wa11 = W0[3];
            wb00 = W0[20]; wb01 = W0[21]; wb10 = W0[22]; wb11 = W0[23];
            bb0 = cc.x; bb1 = cc.y; e0 = cc.z; e1 = cc.w;
        } else {
            const float* wl = Wh + (l - 1) * 8;
            wa00 = wl[0]; wa01 = wl[1]; wa10 = wl[2]; wa11 = wl[3];
            wb00 = wl[4]; wb01 = wl[5]; wb10 = wl[6]; wb11 = wl[7];
            bb0 = bh[(l - 1) * 4 + 0] + bh[(l - 1) * 4 + 2];
            bb1 = bh[(l - 1) * 4 + 1] + bh[(l - 1) * 4 + 3];
            e0 = 0.f; e1 = 0.f;
        }

        float a0 = 0.f, a1 = 0.f;
        for (int c = 0; c < nch; ++c) {
            uint4 w = *(const uint4*)(cp + c * 8);
            GATH(w.x) GATH(w.y) GATH(w.z) GATH(w.w)
        }
        float P0 = dv * a0 + dv2 * x0;
        float P1 = dv * a1 + dv2 * x1;
        float o0 = x0 * wa00 + x1 * wa10 + P0 * wb00 + P1 * wb10 + bb0 + rv * e0;
        float o1 = x0 * wa01 + x1 * wa11 + P0 * wb01 + P1 * wb11 + bb1 + rv * e1;
        x0 = fmaxf(o0, 0.f);
        x1 = fmaxf(o1, 0.f);

        if (l < 7) {
            float2* yb = ybuf + (size_t)l * NN;    // fixed per-layer buffer (same-L2 reuse)
            int* fl = sb + l * 64;                 // 64 per-WAVE flags for this (step,layer)
            yb[n] = make_float2(x0 * dv, x1 * dv);     // wave-contiguous 512B slice
            // per-wave publish: release drains only THIS wave's stores (vmcnt per-wave)
            if ((t & 63) == 0) flag_set(fl + (g << 3) + (t >> 6));
            // every wave polls all 64 flags: one load RT, no intra-WG barrier
            {
                int it = 0;
                for (;;) {
                    int v = __hip_atomic_load(fl + (t & 63), __ATOMIC_RELAXED,
                                              __HIP_MEMORY_SCOPE_AGENT);
                    if (__all(v != 0)) break;
                    __builtin_amdgcn_s_sleep(1);
                    if (++it > (1 << 22)) break;   // safety bail
                }
            }
            (void)__hip_atomic_load(fl + (t & 63), __ATOMIC_ACQUIRE,
                                    __HIP_MEMORY_SCOPE_AGENT);
            asm volatile("" ::: "memory");
            // restage into the OTHER LDS buffer (no conflict with ongoing ycur reads)
            const float4* src = (const float4*)yb;
            float4* dst = (float4*)ynxt;
            #pragma unroll
            for (int k = 0; k < 4; ++k) dst[k * 512 + t] = src[k * 512 + t];
            __syncthreads();                       // single barrier per layer
            float2* tmp = ycur; ycur = ynxt; ynxt = tmp;
        }
    }

    us[n] = x0;
    us[n + NN] = x1;
    // launch boundary provides coherence to k_mv
}

// ---------- per-step matvec: vout = az + m@s + B16 @ u (permuted, conflict-free) ----------
__global__ __launch_bounds__(256) void k_mv(const uint16_t* __restrict__ B16,
                                            const float* __restrict__ u,
                                            const float* __restrict__ az,
                                            const float* __restrict__ m,
                                            const float* __restrict__ s,
                                            float* __restrict__ vout) {
    __shared__ float su[VD];
    int t = threadIdx.x;
    #pragma unroll
    for (int i = 0; i < 8; ++i) {
        int c = i * 1024 + t * 4;
        *(float4*)&su[c] = *(const float4*)&u[c];
    }
    __syncthreads();
    int wave = t >> 6, lane = t & 63;
    int r = blockIdx.x * 4 + wave;
    const uint4* bp = (const uint4*)(B16 + (size_t)r * VD);
    float acc = 0.f;
    #pragma unroll
    for (int jj = 0; jj < 16; ++jj) {
        uint4 w = bp[jj * 64 + lane];          // straight loads: compiler pipelines
        int c = jj * 512 + lane * 4;
        float4 ua = *(float4*)&su[c];          // contiguous 16B/lane: conflict-free
        float4 ub = *(float4*)&su[c + 256];
        acc += bfl(w.x) * ua.x + bfh(w.x) * ua.y + bfl(w.y) * ua.z + bfh(w.y) * ua.w
             + bfl(w.z) * ub.x + bfh(w.z) * ub.y + bfl(w.w) * ub.z + bfh(w.w) * ub.w;
    }
    for (int o = 32; o; o >>= 1) acc += __shfl_down(acc, o);
    if (lane == 0) {
        float cc = 0.f;
        #pragma unroll
        for (int k = 0; k < 8; ++k) cc += s[k] * m[r * 8 + k];
        vout[r] = az[r] + cc + acc;
    }
}

// ---------- launcher ----------
extern "C" void kernel_launch(void* const* d_in, const int* in_sizes, int n_in,
                              void* d_out, int out_size, void* d_ws, size_t ws_size,
                              hipStream_t stream) {
    const float* z   = (const float*)d_in[0];
    const int*   ei  = (const int*)d_in[1];
    const float* A_w = (const float*)d_in[2];
    const float* B_w = (const float*)d_in[3];
    const float* b_w = (const float*)d_in[4];
    const float* se  = (const float*)d_in[5];
    const float* gse = (const float*)d_in[6];
    const float* W0  = (const float*)d_in[7];
    const float* b0  = (const float*)d_in[8];
    const float* Wh  = (const float*)d_in[9];
    const float* bh  = (const float*)d_in[10];

    char* p = (char*)d_ws;
    auto carve = [&](size_t bytes) {
        void* r = (void*)p;
        p += (bytes + 255) & ~(size_t)255;
        return r;
    };
    uint16_t* B16    = (uint16_t*)carve((size_t)VD * VD * 2);
    float*    az     = (float*)carve(VD * 4);
    float*    m      = (float*)carve(VD * 8 * 4);
    float*    v0     = (float*)carve(VD * 4);
    float*    v1     = (float*)carve(VD * 4);
    float*    u      = (float*)carve(VD * 4);
    int*      deg    = (int*)carve(NN * 4);
    int*      fill   = (int*)carve(NN * 4);
    int*      padp   = (int*)carve(NN * 4);
    float*    rr     = (float*)carve(NN * 4);
    float*    dinv   = (float*)carve((NN + 1) * 4);
    uint16_t* csr    = (uint16_t*)carve(CSR_CAP * 2);
    float*    cbuf   = (float*)carve(NSTEPS * 4 * 4);        // per-step layer-0 constants
    float2*   ybuf   = (float2*)carve((size_t)7 * NN * 8);   // 7 fixed exchange buffers (224 KB)
    int*      bar    = (int*)carve((size_t)BARN * 4);        // monotonic per-wave flags (179 KB)

    k_zero<<<CSR_CAP / 2 / 256, 256, 0, stream>>>(deg, fill, v0, (uint32_t*)csr, bar);
    k_deg<<<NE / 256, 256, 0, stream>>>(ei, deg);
    k_scan<<<1, 1024, 0, stream>>>(deg, padp, dinv);
    k_fill<<<NE / 256, 256, 0, stream>>>(ei, padp, fill, csr);
    k_r<<<NN / 256, 256, 0, stream>>>(deg, padp, csr, dinv, rr);
    k_m<<<VD * 8 / 256, 256, 0, stream>>>(A_w, B_w, b_w, m);
    k_c<<<2, 64, 0, stream>>>(W0, b0, gse, cbuf);
    k_az<<<VD / 4, 256, 0, stream>>>(A_w, z, az);
    k_bconv<<<VD * 1024 / 256, 256, 0, stream>>>(B_w, B16);

    const float* vin = v0;
    for (int t = 0; t < NSTEPS; ++t) {
        float* vout = (t == NSTEPS - 1) ? (float*)d_out : ((t & 1) ? v0 : v1);
        k_gnn<<<64, 512, 0, stream>>>(vin, u, ybuf, bar + t * SSTR,
                                      csr, padp, deg, dinv, rr,
                                      W0, b0, Wh, bh, cbuf + 4 * t);
        k_mv<<<VD / 4, 256, 0, stream>>>(B16, u, az, m, se + 8 * t, vout);
        vin = vout;
    }
}

// Round 13
// 5794.448 us; speedup vs baseline: 2.4617x; 2.4617x over previous
//
#include <hip/hip_runtime.h>
#include <stdint.h>

#define NN 4096
#define VD 8192
#define NE 65536
#define NSTEPS 100
#define CSR_CAP 98304  // 65536 + worst-case per-node pad (<= 7*4096) rounded up

#define GWG 8          // GNN workgroups
#define SSTR 64        // flag ints per step (l*8+g for l=0..6, g=0..7; padded)
#define BARN (NSTEPS * SSTR)

typedef unsigned long long u64;

// ---------- helpers ----------
__device__ __forceinline__ uint32_t f2bf(float f) {
    uint32_t x = __float_as_uint(f);
    return (x + 0x7FFFu + ((x >> 16) & 1u)) >> 16;
}
__device__ __forceinline__ float bfl(uint32_t w) { return __uint_as_float(w << 16); }
__device__ __forceinline__ float bfh(uint32_t w) { return __uint_as_float(w & 0xFFFF0000u); }

// system-scope relaxed ops: sc0+sc1 -> bypass L1/L2, coherence at L3.
// No buffer_wbl2 / buffer_inv is ever emitted (the R12 lesson: those cost ~0.2us each).
__device__ __forceinline__ void sys_store64(u64* p, u64 v) {
    __hip_atomic_store(p, v, __ATOMIC_RELAXED, __HIP_MEMORY_SCOPE_SYSTEM);
}
__device__ __forceinline__ u64 sys_load64(const u64* p) {
    return __hip_atomic_load(p, __ATOMIC_RELAXED, __HIP_MEMORY_SCOPE_SYSTEM);
}
__device__ __forceinline__ void sys_store32(int* p, int v) {
    __hip_atomic_store(p, v, __ATOMIC_RELAXED, __HIP_MEMORY_SCOPE_SYSTEM);
}
__device__ __forceinline__ int sys_load32(const int* p) {
    return __hip_atomic_load(p, __ATOMIC_RELAXED, __HIP_MEMORY_SCOPE_SYSTEM);
}

// ---------- setup kernels ----------
__global__ void k_zero(int* deg, int* fill, float* v0, uint32_t* csrw, int* bar) {
    int t = blockIdx.x * 256 + threadIdx.x;           // grid covers 49152
    if (t < 4096) { deg[t] = 0; fill[t] = 0; }
    if (t < 8192) v0[t] = 0.f;
    if (t < BARN) bar[t] = 0;                         // monotonic flags, zeroed per replay
    if (t < CSR_CAP / 2) csrw[t] = 0x10001000u;       // sentinel src = 4096
}

__global__ void k_deg(const int* ei, int* deg) {
    int e = blockIdx.x * 256 + threadIdx.x;
    if (e < NE) atomicAdd(&deg[ei[NE + e]], 1);
}

__global__ __launch_bounds__(1024) void k_scan(const int* deg, int* pad_ptr, float* dinv) {
    __shared__ int sh[1024];
    int t = threadIdx.x;
    int d[4], pl[4], tsum = 0;
    for (int j = 0; j < 4; ++j) {
        d[j] = deg[t * 4 + j];
        pl[j] = (d[j] + 7) & ~7;
        tsum += pl[j];
    }
    sh[t] = tsum;
    __syncthreads();
    for (int off = 1; off < 1024; off <<= 1) {
        int v = sh[t];
        if (t >= off) v += sh[t - off];
        __syncthreads();
        sh[t] = v;
        __syncthreads();
    }
    int base = sh[t] - tsum;  // exclusive prefix
    for (int j = 0; j < 4; ++j) {
        pad_ptr[t * 4 + j] = base;
        base += pl[j];
        dinv[t * 4 + j] = rsqrtf((float)(d[j] + 1));  // +1 self loop, always > 0
    }
    if (t == 0) dinv[4096] = 0.f;  // sentinel
}

__global__ void k_fill(const int* ei, const int* pad_ptr, int* fill, uint16_t* csr) {
    int e = blockIdx.x * 256 + threadIdx.x;
    if (e < NE) {
        int s = ei[e];
        int d = ei[NE + e];
        int pos = atomicAdd(&fill[d], 1);
        csr[pad_ptr[d] + pos] = (uint16_t)s;
    }
}

__global__ void k_r(const int* deg, const int* pad_ptr, const uint16_t* csr,
                    const float* dinv, float* rr) {
    int n = blockIdx.x * 256 + threadIdx.x;
    if (n >= NN) return;
    float dv = dinv[n];
    int base = pad_ptr[n];
    int nch = (deg[n] + 7) >> 3;
    float sum = 0.f;
    for (int c = 0; c < nch; ++c)
        for (int k = 0; k < 8; ++k) sum += dinv[csr[base + c * 8 + k]];  // sentinel adds 0
    rr[n] = dv * sum + dv * dv;
}

__global__ void k_m(const float* A, const float* B, const float* bw, float* m) {
    int t = blockIdx.x * 256 + threadIdx.x;  // 65536
    if (t >= VD * 8) return;
    int i = t >> 3, k = t & 7;
    m[t] = A[(size_t)i * 8200 + 8192 + k] + B[(size_t)i * 8200 + 8192 + k] + bw[i * 8 + k];
}

// per-step layer-0 constants, precomputed once
__global__ void k_c(const float* W0, const float* b0, const float* gse, float* cbuf) {
    int s = blockIdx.x * 64 + threadIdx.x;
    if (s >= NSTEPS) return;
    const float* gs = gse + 8 * s;
    float c0_0 = b0[0] + b0[2], c0_1 = b0[1] + b0[3];
    float c1_0 = 0.f, c1_1 = 0.f;
    for (int k = 0; k < 8; ++k) {
        float sv = gs[k];
        c0_0 += sv * W0[(2 + k) * 2 + 0];
        c0_1 += sv * W0[(2 + k) * 2 + 1];
        c1_0 += sv * W0[20 + (2 + k) * 2 + 0];
        c1_1 += sv * W0[20 + (2 + k) * 2 + 1];
    }
    ((float4*)cbuf)[s] = make_float4(c0_0, c0_1, c1_0, c1_1);
}

__global__ __launch_bounds__(256) void k_az(const float* A, const float* z, float* az) {
    int wave = threadIdx.x >> 6, lane = threadIdx.x & 63;
    int r = blockIdx.x * 4 + wave;
    const float* row = A + (size_t)r * 8200;
    float acc = 0.f;
    for (int j = 0; j < 32; ++j) {
        int c = j * 256 + lane * 4;
        float4 a = *(const float4*)(row + c);
        float4 zz = *(const float4*)(z + c);
        acc += a.x * zz.x + a.y * zz.y + a.z * zz.z + a.w * zz.w;
    }
    for (int o = 32; o; o >>= 1) acc += __shfl_down(acc, o);
    if (lane == 0) az[r] = acc;
}

// Permuted B16 layout: row r, uint4 index p = jj*64 + l holds bf16 of cols
// {jj*512+4l .. +3} (words x,y) and {jj*512+256+4l .. +3} (words z,w).
// This makes the mv-phase su reads contiguous 16B/lane -> conflict-free LDS.
__global__ __launch_bounds__(256) void k_bconv(const float* B, uint16_t* B16) {
    int t = blockIdx.x * 256 + threadIdx.x;  // VD*1024 threads, one uint4 each
    int i = t >> 10;
    int p = t & 1023;
    int jj = p >> 6, l = p & 63;
    const float* pr = B + (size_t)i * 8200 + jj * 512 + l * 4;
    float4 a = *(const float4*)pr;
    float4 b = *(const float4*)(pr + 256);
    uint4 w;
    w.x = f2bf(a.x) | (f2bf(a.y) << 16);
    w.y = f2bf(a.z) | (f2bf(a.w) << 16);
    w.z = f2bf(b.x) | (f2bf(b.y) << 16);
    w.w = f2bf(b.z) | (f2bf(b.w) << 16);
    ((uint4*)B16)[t] = w;
}

// ---------- per-step GNN: 8 WGs, L3-routed exchange (no cache-maintenance ops) ----------
#define GATH(W) { float2 yy0 = y[(W) & 0xFFFFu]; a0 += yy0.x; a1 += yy0.y; \
                  float2 yy1 = y[(W) >> 16];     a0 += yy1.x; a1 += yy1.y; }

__global__ __launch_bounds__(512) void k_gnn(
    const float* __restrict__ vin, float* __restrict__ us,
    u64* __restrict__ ybuf, int* __restrict__ sb,
    const uint16_t* __restrict__ csr, const int* __restrict__ pad_ptr,
    const int* __restrict__ deg, const float* __restrict__ dinv,
    const float* __restrict__ rr,
    const float* __restrict__ W0, const float* __restrict__ b0,
    const float* __restrict__ Wh, const float* __restrict__ bh,
    const float* __restrict__ cst) {
    __shared__ float2 y[NN + 1];         // y[n] = x[n]*dinv[n]; y[4096] = 0 sentinel
    const int g = blockIdx.x;            // 0..7
    const int t = threadIdx.x;           // 0..511
    const int n = g * 512 + t;

    const float dv = dinv[n], rv = rr[n], dv2 = dv * dv;
    const int base = pad_ptr[n];
    const int nch = (deg[n] + 7) >> 3;
    const uint16_t* cp = csr + base;
    float dmy[8];
    #pragma unroll
    for (int j = 0; j < 8; ++j) dmy[j] = dinv[j * 512 + t];

    const float4 cc = *(const float4*)cst;   // precomputed layer-0 step constants

    float x0 = vin[n], x1 = vin[n + NN];
    #pragma unroll
    for (int j = 0; j < 8; ++j) {
        int mm = j * 512 + t;
        y[mm] = make_float2(vin[mm] * dmy[j], vin[mm + NN] * dmy[j]);
    }
    if (t == 0) y[NN] = make_float2(0.f, 0.f);
    __syncthreads();

    for (int l = 0; l < 8; ++l) {
        float wa00, wa01, wa10, wa11, wb00, wb01, wb10, wb11, bb0, bb1, e0, e1;
        if (l == 0) {
            wa00 = W0[0]; wa01 = W0[1]; wa10 = W0[2]; wa11 = W0[3];
            wb00 = W0[20]; wb01 = W0[21]; wb10 = W0[22]; wb11 = W0[23];
            bb0 = cc.x; bb1 = cc.y; e0 = cc.z; e1 = cc.w;
        } else {
            const float* wl = Wh + (l - 1) * 8;
            wa00 = wl[0]; wa01 = wl[1]; wa10 = wl[2]; wa11 = wl[3];
            wb00 = wl[4]; wb01 = wl[5]; wb10 = wl[6]; wb11 = wl[7];
            bb0 = bh[(l - 1) * 4 + 0] + bh[(l - 1) * 4 + 2];
            bb1 = bh[(l - 1) * 4 + 1] + bh[(l - 1) * 4 + 3];
            e0 = 0.f; e1 = 0.f;
        }

        float a0 = 0.f, a1 = 0.f;
        for (int c = 0; c < nch; ++c) {
            uint4 w = *(const uint4*)(cp + c * 8);
            GATH(w.x) GATH(w.y) GATH(w.z) GATH(w.w)
        }
        float P0 = dv * a0 + dv2 * x0;
        float P1 = dv * a1 + dv2 * x1;
        float o0 = x0 * wa00 + x1 * wa10 + P0 * wb00 + P1 * wb10 + bb0 + rv * e0;
        float o1 = x0 * wa01 + x1 * wa11 + P0 * wb01 + P1 * wb11 + bb1 + rv * e1;
        x0 = fmaxf(o0, 0.f);
        x1 = fmaxf(o1, 0.f);

        if (l < 7) {
            u64* yb = ybuf + (size_t)l * NN;       // fixed per-layer buffer (L3-routed)
            int* fl = sb + l * 8;                  // 8 per-WG flags for this (step,layer)
            // publish own value straight to L3 (bypasses L1/L2 -> no wbl2 needed ever)
            float2 val = make_float2(x0 * dv, x1 * dv);
            u64 bits = ((u64)__float_as_uint(val.y) << 32) | __float_as_uint(val.x);
            sys_store64(yb + n, bits);
            __syncthreads();    // LDS reads of y done; vmcnt(0) drains store acks (L3 pt)
            if (t == 0) sys_store32(fl + g, 1);    // flag: L3-visible after data
            if (t < 64) {                          // wave 0: 8-lane parallel poll, 1 L3 RT
                int it = 0;
                for (;;) {
                    int v = (t < 8) ? sys_load32(fl + t) : 1;
                    if (__all(v != 0)) break;
                    __builtin_amdgcn_s_sleep(1);
                    if (++it > (1 << 22)) break;   // safety bail
                }
            }
            __syncthreads();
            asm volatile("" ::: "memory");
            // restage full y from L3 (8B system loads: no stale-cache channel at all)
            #pragma unroll
            for (int k = 0; k < 8; ++k) {
                u64 b = sys_load64(yb + k * 512 + t);
                y[k * 512 + t] = make_float2(__uint_as_float((uint32_t)b),
                                             __uint_as_float((uint32_t)(b >> 32)));
            }
            __syncthreads();
        }
    }

    us[n] = x0;
    us[n + NN] = x1;
    // launch boundary provides coherence to k_mv
}

// ---------- per-step matvec: vout = az + m@s + B16 @ u (permuted, conflict-free) ----------
__global__ __launch_bounds__(256) void k_mv(const uint16_t* __restrict__ B16,
                                            const float* __restrict__ u,
                                            const float* __restrict__ az,
                                            const float* __restrict__ m,
                                            const float* __restrict__ s,
                                            float* __restrict__ vout) {
    __shared__ float su[VD];
    int t = threadIdx.x;
    #pragma unroll
    for (int i = 0; i < 8; ++i) {
        int c = i * 1024 + t * 4;
        *(float4*)&su[c] = *(const float4*)&u[c];
    }
    __syncthreads();
    int wave = t >> 6, lane = t & 63;
    int r = blockIdx.x * 4 + wave;
    const uint4* bp = (const uint4*)(B16 + (size_t)r * VD);
    float acc = 0.f;
    #pragma unroll
    for (int jj = 0; jj < 16; ++jj) {
        uint4 w = bp[jj * 64 + lane];          // straight loads: compiler pipelines
        int c = jj * 512 + lane * 4;
        float4 ua = *(float4*)&su[c];          // contiguous 16B/lane: conflict-free
        float4 ub = *(float4*)&su[c + 256];
        acc += bfl(w.x) * ua.x + bfh(w.x) * ua.y + bfl(w.y) * ua.z + bfh(w.y) * ua.w
             + bfl(w.z) * ub.x + bfh(w.z) * ub.y + bfl(w.w) * ub.z + bfh(w.w) * ub.w;
    }
    for (int o = 32; o; o >>= 1) acc += __shfl_down(acc, o);
    if (lane == 0) {
        float cc = 0.f;
        #pragma unroll
        for (int k = 0; k < 8; ++k) cc += s[k] * m[r * 8 + k];
        vout[r] = az[r] + cc + acc;
    }
}

// ---------- launcher ----------
extern "C" void kernel_launch(void* const* d_in, const int* in_sizes, int n_in,
                              void* d_out, int out_size, void* d_ws, size_t ws_size,
                              hipStream_t stream) {
    const float* z   = (const float*)d_in[0];
    const int*   ei  = (const int*)d_in[1];
    const float* A_w = (const float*)d_in[2];
    const float* B_w = (const float*)d_in[3];
    const float* b_w = (const float*)d_in[4];
    const float* se  = (const float*)d_in[5];
    const float* gse = (const float*)d_in[6];
    const float* W0  = (const float*)d_in[7];
    const float* b0  = (const float*)d_in[8];
    const float* Wh  = (const float*)d_in[9];
    const float* bh  = (const float*)d_in[10];

    char* p = (char*)d_ws;
    auto carve = [&](size_t bytes) {
        void* r = (void*)p;
        p += (bytes + 255) & ~(size_t)255;
        return r;
    };
    uint16_t* B16    = (uint16_t*)carve((size_t)VD * VD * 2);
    float*    az     = (float*)carve(VD * 4);
    float*    m      = (float*)carve(VD * 8 * 4);
    float*    v0     = (float*)carve(VD * 4);
    float*    v1     = (float*)carve(VD * 4);
    float*    u      = (float*)carve(VD * 4);
    int*      deg    = (int*)carve(NN * 4);
    int*      fill   = (int*)carve(NN * 4);
    int*      padp   = (int*)carve(NN * 4);
    float*    rr     = (float*)carve(NN * 4);
    float*    dinv   = (float*)carve((NN + 1) * 4);
    uint16_t* csr    = (uint16_t*)carve(CSR_CAP * 2);
    float*    cbuf   = (float*)carve(NSTEPS * 4 * 4);        // per-step layer-0 constants
    u64*      ybuf   = (u64*)carve((size_t)7 * NN * 8);      // 7 fixed exchange buffers
    int*      bar    = (int*)carve((size_t)BARN * 4);        // monotonic flags

    k_zero<<<CSR_CAP / 2 / 256, 256, 0, stream>>>(deg, fill, v0, (uint32_t*)csr, bar);
    k_deg<<<NE / 256, 256, 0, stream>>>(ei, deg);
    k_scan<<<1, 1024, 0, stream>>>(deg, padp, dinv);
    k_fill<<<NE / 256, 256, 0, stream>>>(ei, padp, fill, csr);
    k_r<<<NN / 256, 256, 0, stream>>>(deg, padp, csr, dinv, rr);
    k_m<<<VD * 8 / 256, 256, 0, stream>>>(A_w, B_w, b_w, m);
    k_c<<<2, 64, 0, stream>>>(W0, b0, gse, cbuf);
    k_az<<<VD / 4, 256, 0, stream>>>(A_w, z, az);
    k_bconv<<<VD * 1024 / 256, 256, 0, stream>>>(B_w, B16);

    const float* vin = v0;
    for (int t = 0; t < NSTEPS; ++t) {
        float* vout = (t == NSTEPS - 1) ? (float*)d_out : ((t & 1) ? v0 : v1);
        k_gnn<<<GWG, 512, 0, stream>>>(vin, u, ybuf, bar + t * SSTR,
                                       csr, padp, deg, dinv, rr,
                                       W0, b0, Wh, bh, cbuf + 4 * t);
        k_mv<<<VD / 4, 256, 0, stream>>>(B16, u, az, m, se + 8 * t, vout);
        vin = vout;
    }
}

// Round 14
// 5250.000 us; speedup vs baseline: 2.7170x; 1.1037x over previous
//
#include <hip/hip_runtime.h>
#include <stdint.h>

#define NN 4096
#define VD 8192
#define NE 65536
#define NSTEPS 100
#define CSR_CAP 98304  // 65536 + worst-case per-node pad (<= 7*4096) rounded up

#define GWG 8          // GNN workgroups (active bids 0,8,...,56 of a 64-block launch)
#define SSTR 64        // flag ints per step (l*8+g for l=0..6, g=0..7)
#define BARN (NSTEPS * SSTR)

// ---------- helpers ----------
__device__ __forceinline__ uint32_t f2bf(float f) {
    uint32_t x = __float_as_uint(f);
    return (x + 0x7FFFu + ((x >> 16) & 1u)) >> 16;
}
__device__ __forceinline__ float bfl(uint32_t w) { return __uint_as_float(w << 16); }
__device__ __forceinline__ float bfh(uint32_t w) { return __uint_as_float(w & 0xFFFF0000u); }

__device__ __forceinline__ void flag_set(int* f) {
    // release: prior yb stores already vmcnt-drained by __syncthreads; pushes to L2
    __hip_atomic_store(f, 1, __ATOMIC_RELEASE, __HIP_MEMORY_SCOPE_AGENT);
}

// ---------- setup kernels ----------
__global__ void k_zero(int* deg, int* fill, float* v0, uint32_t* csrw, int* bar) {
    int t = blockIdx.x * 256 + threadIdx.x;           // grid covers 49152
    if (t < 4096) { deg[t] = 0; fill[t] = 0; }
    if (t < 8192) v0[t] = 0.f;
    if (t < BARN) bar[t] = 0;                         // monotonic flags, zeroed per replay
    if (t < CSR_CAP / 2) csrw[t] = 0x10001000u;       // sentinel src = 4096
}

__global__ void k_deg(const int* ei, int* deg) {
    int e = blockIdx.x * 256 + threadIdx.x;
    if (e < NE) atomicAdd(&deg[ei[NE + e]], 1);
}

__global__ __launch_bounds__(1024) void k_scan(const int* deg, int* pad_ptr, float* dinv) {
    __shared__ int sh[1024];
    int t = threadIdx.x;
    int d[4], pl[4], tsum = 0;
    for (int j = 0; j < 4; ++j) {
        d[j] = deg[t * 4 + j];
        pl[j] = (d[j] + 7) & ~7;
        tsum += pl[j];
    }
    sh[t] = tsum;
    __syncthreads();
    for (int off = 1; off < 1024; off <<= 1) {
        int v = sh[t];
        if (t >= off) v += sh[t - off];
        __syncthreads();
        sh[t] = v;
        __syncthreads();
    }
    int base = sh[t] - tsum;  // exclusive prefix
    for (int j = 0; j < 4; ++j) {
        pad_ptr[t * 4 + j] = base;
        base += pl[j];
        dinv[t * 4 + j] = rsqrtf((float)(d[j] + 1));  // +1 self loop, always > 0
    }
    if (t == 0) dinv[4096] = 0.f;  // sentinel
}

__global__ void k_fill(const int* ei, const int* pad_ptr, int* fill, uint16_t* csr) {
    int e = blockIdx.x * 256 + threadIdx.x;
    if (e < NE) {
        int s = ei[e];
        int d = ei[NE + e];
        int pos = atomicAdd(&fill[d], 1);
        csr[pad_ptr[d] + pos] = (uint16_t)s;
    }
}

__global__ void k_r(const int* deg, const int* pad_ptr, const uint16_t* csr,
                    const float* dinv, float* rr) {
    int n = blockIdx.x * 256 + threadIdx.x;
    if (n >= NN) return;
    float dv = dinv[n];
    int base = pad_ptr[n];
    int nch = (deg[n] + 7) >> 3;
    float sum = 0.f;
    for (int c = 0; c < nch; ++c)
        for (int k = 0; k < 8; ++k) sum += dinv[csr[base + c * 8 + k]];  // sentinel adds 0
    rr[n] = dv * sum + dv * dv;
}

__global__ void k_m(const float* A, const float* B, const float* bw, float* m) {
    int t = blockIdx.x * 256 + threadIdx.x;  // 65536
    if (t >= VD * 8) return;
    int i = t >> 3, k = t & 7;
    m[t] = A[(size_t)i * 8200 + 8192 + k] + B[(size_t)i * 8200 + 8192 + k] + bw[i * 8 + k];
}

// per-step layer-0 constants, precomputed once (hoisted out of k_gnn's prologue)
__global__ void k_c(const float* W0, const float* b0, const float* gse, float* cbuf) {
    int s = blockIdx.x * 64 + threadIdx.x;
    if (s >= NSTEPS) return;
    const float* gs = gse + 8 * s;
    float c0_0 = b0[0] + b0[2], c0_1 = b0[1] + b0[3];
    float c1_0 = 0.f, c1_1 = 0.f;
    for (int k = 0; k < 8; ++k) {
        float sv = gs[k];
        c0_0 += sv * W0[(2 + k) * 2 + 0];
        c0_1 += sv * W0[(2 + k) * 2 + 1];
        c1_0 += sv * W0[20 + (2 + k) * 2 + 0];
        c1_1 += sv * W0[20 + (2 + k) * 2 + 1];
    }
    ((float4*)cbuf)[s] = make_float4(c0_0, c0_1, c1_0, c1_1);
}

__global__ __launch_bounds__(256) void k_az(const float* A, const float* z, float* az) {
    int wave = threadIdx.x >> 6, lane = threadIdx.x & 63;
    int r = blockIdx.x * 4 + wave;
    const float* row = A + (size_t)r * 8200;
    float acc = 0.f;
    for (int j = 0; j < 32; ++j) {
        int c = j * 256 + lane * 4;
        float4 a = *(const float4*)(row + c);
        float4 zz = *(const float4*)(z + c);
        acc += a.x * zz.x + a.y * zz.y + a.z * zz.z + a.w * zz.w;
    }
    for (int o = 32; o; o >>= 1) acc += __shfl_down(acc, o);
    if (lane == 0) az[r] = acc;
}

// Permuted B16 layout: row r, uint4 index p = jj*64 + l holds bf16 of cols
// {jj*512+4l .. +3} (words x,y) and {jj*512+256+4l .. +3} (words z,w).
// This makes the mv-phase su reads contiguous 16B/lane -> conflict-free LDS.
__global__ __launch_bounds__(256) void k_bconv(const float* B, uint16_t* B16) {
    int t = blockIdx.x * 256 + threadIdx.x;  // VD*1024 threads, one uint4 each
    int i = t >> 10;
    int p = t & 1023;
    int jj = p >> 6, l = p & 63;
    const float* pr = B + (size_t)i * 8200 + jj * 512 + l * 4;
    float4 a = *(const float4*)pr;
    float4 b = *(const float4*)(pr + 256);
    uint4 w;
    w.x = f2bf(a.x) | (f2bf(a.y) << 16);
    w.y = f2bf(a.z) | (f2bf(a.w) << 16);
    w.z = f2bf(b.x) | (f2bf(b.y) << 16);
    w.w = f2bf(b.z) | (f2bf(b.w) << 16);
    ((uint4*)B16)[t] = w;
}

// ---------- per-step GNN: 8 active WGs (same XCD -> same L2), fixed small y buffers ----------
#define GATH(W) { float2 yy0 = y[(W) & 0xFFFFu]; a0 += yy0.x; a1 += yy0.y; \
                  float2 yy1 = y[(W) >> 16];     a0 += yy1.x; a1 += yy1.y; }

__global__ __launch_bounds__(512) void k_gnn(
    const float* __restrict__ vin, float* __restrict__ us,
    float2* __restrict__ ybuf, int* __restrict__ sb,
    const uint16_t* __restrict__ csr, const int* __restrict__ pad_ptr,
    const int* __restrict__ deg, const float* __restrict__ dinv,
    const float* __restrict__ rr,
    const float* __restrict__ W0, const float* __restrict__ b0,
    const float* __restrict__ Wh, const float* __restrict__ bh,
    const float* __restrict__ cst) {
    const int bid = blockIdx.x;
    if (bid & 7) return;                 // active: 0,8,..,56 -> one XCD under bid%8 round-robin
    __shared__ float2 y[NN + 1];         // y[n] = x[n]*dinv[n]; y[4096] = 0 sentinel
    const int g = bid >> 3;              // 0..7
    const int t = threadIdx.x;           // 0..511
    const int n = g * 512 + t;

    const float dv = dinv[n], rv = rr[n], dv2 = dv * dv;
    const int base = pad_ptr[n];
    const int nch = (deg[n] + 7) >> 3;
    const uint16_t* cp = csr + base;
    float dmy[8];
    #pragma unroll
    for (int j = 0; j < 8; ++j) dmy[j] = dinv[j * 512 + t];

    const float4 cc = *(const float4*)cst;   // precomputed layer-0 step constants

    float x0 = vin[n], x1 = vin[n + NN];
    #pragma unroll
    for (int j = 0; j < 8; ++j) {
        int mm = j * 512 + t;
        y[mm] = make_float2(vin[mm] * dmy[j], vin[mm + NN] * dmy[j]);
    }
    if (t == 0) y[NN] = make_float2(0.f, 0.f);
    __syncthreads();

    for (int l = 0; l < 8; ++l) {
        float wa00, wa01, wa10, wa11, wb00, wb01, wb10, wb11, bb0, bb1, e0, e1;
        if (l == 0) {
            wa00 = W0[0]; wa01 = W0[1]; wa10 = W0[2]; wa11 = W0[3];
            wb00 = W0[20]; wb01 = W0[21]; wb10 = W0[22]; wb11 = W0[23];
            bb0 = cc.x; bb1 = cc.y; e0 = cc.z; e1 = cc.w;
        } else {
            const float* wl = Wh + (l - 1) * 8;
            wa00 = wl[0]; wa01 = wl[1]; wa10 = wl[2]; wa11 = wl[3];
            wb00 = wl[4]; wb01 = wl[5]; wb10 = wl[6]; wb11 = wl[7];
            bb0 = bh[(l - 1) * 4 + 0] + bh[(l - 1) * 4 + 2];
            bb1 = bh[(l - 1) * 4 + 1] + bh[(l - 1) * 4 + 3];
            e0 = 0.f; e1 = 0.f;
        }

        float a0 = 0.f, a1 = 0.f;
        for (int c = 0; c < nch; ++c) {
            uint4 w = *(const uint4*)(cp + c * 8);
            GATH(w.x) GATH(w.y) GATH(w.z) GATH(w.w)
        }
        float P0 = dv * a0 + dv2 * x0;
        float P1 = dv * a1 + dv2 * x1;
        float o0 = x0 * wa00 + x1 * wa10 + P0 * wb00 + P1 * wb10 + bb0 + rv * e0;
        float o1 = x0 * wa01 + x1 * wa11 + P0 * wb01 + P1 * wb11 + bb1 + rv * e1;
        x0 = fmaxf(o0, 0.f);
        x1 = fmaxf(o1, 0.f);

        if (l < 7) {
            float2* yb = ybuf + (size_t)l * NN;    // fixed per-layer buffer (same-L2 reuse)
            int* fl = sb + l * 8;                  // 8 per-WG flags for this (step,layer)
            yb[n] = make_float2(x0 * dv, x1 * dv);
            __syncthreads();            // LDS reads done; yb stores vmcnt-drained
            if (t == 0) flag_set(fl + g);          // parallel release stores
            if (t < 64) {                          // wave 0: 8-lane parallel poll
                int it = 0;
                for (;;) {
                    int v = (t < 8) ? __hip_atomic_load(fl + t, __ATOMIC_RELAXED,
                                                        __HIP_MEMORY_SCOPE_AGENT) : 1;
                    if (__all(v != 0)) break;
                    __builtin_amdgcn_s_sleep(1);
                    if (++it > (1 << 22)) break;   // safety bail
                }
            }
            __syncthreads();
            asm volatile("" ::: "memory");
            const float4* src = (const float4*)yb;   // same-L2 hits
            float4* dst = (float4*)y;
            #pragma unroll
            for (int k = 0; k < 4; ++k) dst[k * 512 + t] = src[k * 512 + t];
            __syncthreads();
        }
    }

    us[n] = x0;
    us[n + NN] = x1;
    // launch boundary provides coherence to k_mv
}

// ---------- per-step matvec: vout = az + m@s + B16 @ u (permuted, conflict-free) ----------
__global__ __launch_bounds__(256) void k_mv(const uint16_t* __restrict__ B16,
                                            const float* __restrict__ u,
                                            const float* __restrict__ az,
                                            const float* __restrict__ m,
                                            const float* __restrict__ s,
                                            float* __restrict__ vout) {
    __shared__ float su[VD];
    int t = threadIdx.x;
    #pragma unroll
    for (int i = 0; i < 8; ++i) {
        int c = i * 1024 + t * 4;
        *(float4*)&su[c] = *(const float4*)&u[c];
    }
    __syncthreads();
    int wave = t >> 6, lane = t & 63;
    int r = blockIdx.x * 4 + wave;
    const uint4* bp = (const uint4*)(B16 + (size_t)r * VD);
    float acc = 0.f;
    #pragma unroll
    for (int jj = 0; jj < 16; ++jj) {
        uint4 w = bp[jj * 64 + lane];          // straight loads: compiler pipelines
        int c = jj * 512 + lane * 4;
        float4 ua = *(float4*)&su[c];          // contiguous 16B/lane: conflict-free
        float4 ub = *(float4*)&su[c + 256];
        acc += bfl(w.x) * ua.x + bfh(w.x) * ua.y + bfl(w.y) * ua.z + bfh(w.y) * ua.w
             + bfl(w.z) * ub.x + bfh(w.z) * ub.y + bfl(w.w) * ub.z + bfh(w.w) * ub.w;
    }
    for (int o = 32; o; o >>= 1) acc += __shfl_down(acc, o);
    if (lane == 0) {
        float cc = 0.f;
        #pragma unroll
        for (int k = 0; k < 8; ++k) cc += s[k] * m[r * 8 + k];
        vout[r] = az[r] + cc + acc;
    }
}

// ---------- launcher ----------
extern "C" void kernel_launch(void* const* d_in, const int* in_sizes, int n_in,
                              void* d_out, int out_size, void* d_ws, size_t ws_size,
                              hipStream_t stream) {
    const float* z   = (const float*)d_in[0];
    const int*   ei  = (const int*)d_in[1];
    const float* A_w = (const float*)d_in[2];
    const float* B_w = (const float*)d_in[3];
    const float* b_w = (const float*)d_in[4];
    const float* se  = (const float*)d_in[5];
    const float* gse = (const float*)d_in[6];
    const float* W0  = (const float*)d_in[7];
    const float* b0  = (const float*)d_in[8];
    const float* Wh  = (const float*)d_in[9];
    const float* bh  = (const float*)d_in[10];

    char* p = (char*)d_ws;
    auto carve = [&](size_t bytes) {
        void* r = (void*)p;
        p += (bytes + 255) & ~(size_t)255;
        return r;
    };
    uint16_t* B16    = (uint16_t*)carve((size_t)VD * VD * 2);
    float*    az     = (float*)carve(VD * 4);
    float*    m      = (float*)carve(VD * 8 * 4);
    float*    v0     = (float*)carve(VD * 4);
    float*    v1     = (float*)carve(VD * 4);
    float*    u      = (float*)carve(VD * 4);
    int*      deg    = (int*)carve(NN * 4);
    int*      fill   = (int*)carve(NN * 4);
    int*      padp   = (int*)carve(NN * 4);
    float*    rr     = (float*)carve(NN * 4);
    float*    dinv   = (float*)carve((NN + 1) * 4);
    uint16_t* csr    = (uint16_t*)carve(CSR_CAP * 2);
    float*    cbuf   = (float*)carve(NSTEPS * 4 * 4);        // per-step layer-0 constants
    float2*   ybuf   = (float2*)carve((size_t)7 * NN * 8);   // 7 fixed exchange buffers (224 KB)
    int*      bar    = (int*)carve((size_t)BARN * 4);        // monotonic flags (25.6 KB)

    k_zero<<<CSR_CAP / 2 / 256, 256, 0, stream>>>(deg, fill, v0, (uint32_t*)csr, bar);
    k_deg<<<NE / 256, 256, 0, stream>>>(ei, deg);
    k_scan<<<1, 1024, 0, stream>>>(deg, padp, dinv);
    k_fill<<<NE / 256, 256, 0, stream>>>(ei, padp, fill, csr);
    k_r<<<NN / 256, 256, 0, stream>>>(deg, padp, csr, dinv, rr);
    k_m<<<VD * 8 / 256, 256, 0, stream>>>(A_w, B_w, b_w, m);
    k_c<<<2, 64, 0, stream>>>(W0, b0, gse, cbuf);
    k_az<<<VD / 4, 256, 0, stream>>>(A_w, z, az);
    k_bconv<<<VD * 1024 / 256, 256, 0, stream>>>(B_w, B16);

    const float* vin = v0;
    for (int t = 0; t < NSTEPS; ++t) {
        float* vout = (t == NSTEPS - 1) ? (float*)d_out : ((t & 1) ? v0 : v1);
        k_gnn<<<64, 512, 0, stream>>>(vin, u, ybuf, bar + t * SSTR,
                                      csr, padp, deg, dinv, rr,
                                      W0, b0, Wh, bh, cbuf + 4 * t);
        k_mv<<<VD / 4, 256, 0, stream>>>(B16, u, az, m, se + 8 * t, vout);
        vin = vout;
    }
}

// Round 15
// 4504.638 us; speedup vs baseline: 3.1665x; 1.1655x over previous
//
#include <hip/hip_runtime.h>
#include <stdint.h>

#define NN 4096
#define VD 8192
#define NE 65536
#define NSTEPS 100
#define CSR_CAP 98304  // 65536 + worst-case per-node pad (<= 7*4096) rounded up

#define GWG 8          // GNN workgroups (active bids 0,8,...,56 of a 64-block launch)
#define SSTR 64        // flag ints per step (l*8+g for l=0..6, g=0..7)
#define BARN (NSTEPS * SSTR)

// ---------- helpers ----------
__device__ __forceinline__ uint32_t f2bf(float f) {
    uint32_t x = __float_as_uint(f);
    return (x + 0x7FFFu + ((x >> 16) & 1u)) >> 16;
}
__device__ __forceinline__ float bfl(uint32_t w) { return __uint_as_float(w << 16); }
__device__ __forceinline__ float bfh(uint32_t w) { return __uint_as_float(w & 0xFFFF0000u); }

__device__ __forceinline__ void flag_set(int* f) {
    // RELAXED, not release: data stores are already L2-ACKed (vmcnt(0) drained by the
    // preceding __syncthreads), and producer+consumer share one XCD L2 (bid placement).
    // Release's buffer_wbl2 (~0.2-0.5us, R12 measurement) is pure overhead here.
    __hip_atomic_store(f, 1, __ATOMIC_RELAXED, __HIP_MEMORY_SCOPE_AGENT);
}

// ---------- setup kernels ----------
__global__ void k_zero(int* deg, int* fill, float* v0, uint32_t* csrw, int* bar) {
    int t = blockIdx.x * 256 + threadIdx.x;           // grid covers 49152
    if (t < 4096) { deg[t] = 0; fill[t] = 0; }
    if (t < 8192) v0[t] = 0.f;
    if (t < BARN) bar[t] = 0;                         // monotonic flags, zeroed per replay
    if (t < CSR_CAP / 2) csrw[t] = 0x10001000u;       // sentinel src = 4096
}

__global__ void k_deg(const int* ei, int* deg) {
    int e = blockIdx.x * 256 + threadIdx.x;
    if (e < NE) atomicAdd(&deg[ei[NE + e]], 1);
}

__global__ __launch_bounds__(1024) void k_scan(const int* deg, int* pad_ptr, float* dinv) {
    __shared__ int sh[1024];
    int t = threadIdx.x;
    int d[4], pl[4], tsum = 0;
    for (int j = 0; j < 4; ++j) {
        d[j] = deg[t * 4 + j];
        pl[j] = (d[j] + 7) & ~7;
        tsum += pl[j];
    }
    sh[t] = tsum;
    __syncthreads();
    for (int off = 1; off < 1024; off <<= 1) {
        int v = sh[t];
        if (t >= off) v += sh[t - off];
        __syncthreads();
        sh[t] = v;
        __syncthreads();
    }
    int base = sh[t] - tsum;  // exclusive prefix
    for (int j = 0; j < 4; ++j) {
        pad_ptr[t * 4 + j] = base;
        base += pl[j];
        dinv[t * 4 + j] = rsqrtf((float)(d[j] + 1));  // +1 self loop, always > 0
    }
    if (t == 0) dinv[4096] = 0.f;  // sentinel
}

__global__ void k_fill(const int* ei, const int* pad_ptr, int* fill, uint16_t* csr) {
    int e = blockIdx.x * 256 + threadIdx.x;
    if (e < NE) {
        int s = ei[e];
        int d = ei[NE + e];
        int pos = atomicAdd(&fill[d], 1);
        csr[pad_ptr[d] + pos] = (uint16_t)s;
    }
}

__global__ void k_r(const int* deg, const int* pad_ptr, const uint16_t* csr,
                    const float* dinv, float* rr) {
    int n = blockIdx.x * 256 + threadIdx.x;
    if (n >= NN) return;
    float dv = dinv[n];
    int base = pad_ptr[n];
    int nch = (deg[n] + 7) >> 3;
    float sum = 0.f;
    for (int c = 0; c < nch; ++c)
        for (int k = 0; k < 8; ++k) sum += dinv[csr[base + c * 8 + k]];  // sentinel adds 0
    rr[n] = dv * sum + dv * dv;
}

__global__ void k_m(const float* A, const float* B, const float* bw, float* m) {
    int t = blockIdx.x * 256 + threadIdx.x;  // 65536
    if (t >= VD * 8) return;
    int i = t >> 3, k = t & 7;
    m[t] = A[(size_t)i * 8200 + 8192 + k] + B[(size_t)i * 8200 + 8192 + k] + bw[i * 8 + k];
}

// per-step layer-0 constants, precomputed once (hoisted out of k_gnn's prologue)
__global__ void k_c(const float* W0, const float* b0, const float* gse, float* cbuf) {
    int s = blockIdx.x * 64 + threadIdx.x;
    if (s >= NSTEPS) return;
    const float* gs = gse + 8 * s;
    float c0_0 = b0[0] + b0[2], c0_1 = b0[1] + b0[3];
    float c1_0 = 0.f, c1_1 = 0.f;
    for (int k = 0; k < 8; ++k) {
        float sv = gs[k];
        c0_0 += sv * W0[(2 + k) * 2 + 0];
        c0_1 += sv * W0[(2 + k) * 2 + 1];
        c1_0 += sv * W0[20 + (2 + k) * 2 + 0];
        c1_1 += sv * W0[20 + (2 + k) * 2 + 1];
    }
    ((float4*)cbuf)[s] = make_float4(c0_0, c0_1, c1_0, c1_1);
}

__global__ __launch_bounds__(256) void k_az(const float* A, const float* z, float* az) {
    int wave = threadIdx.x >> 6, lane = threadIdx.x & 63;
    int r = blockIdx.x * 4 + wave;
    const float* row = A + (size_t)r * 8200;
    float acc = 0.f;
    for (int j = 0; j < 32; ++j) {
        int c = j * 256 + lane * 4;
        float4 a = *(const float4*)(row + c);
        float4 zz = *(const float4*)(z + c);
        acc += a.x * zz.x + a.y * zz.y + a.z * zz.z + a.w * zz.w;
    }
    for (int o = 32; o; o >>= 1) acc += __shfl_down(acc, o);
    if (lane == 0) az[r] = acc;
}

// Permuted B16 layout: row r, uint4 index p = jj*64 + l holds bf16 of cols
// {jj*512+4l .. +3} (words x,y) and {jj*512+256+4l .. +3} (words z,w).
// This makes the mv-phase su reads contiguous 16B/lane -> conflict-free LDS.
__global__ __launch_bounds__(256) void k_bconv(const float* B, uint16_t* B16) {
    int t = blockIdx.x * 256 + threadIdx.x;  // VD*1024 threads, one uint4 each
    int i = t >> 10;
    int p = t & 1023;
    int jj = p >> 6, l = p & 63;
    const float* pr = B + (size_t)i * 8200 + jj * 512 + l * 4;
    float4 a = *(const float4*)pr;
    float4 b = *(const float4*)(pr + 256);
    uint4 w;
    w.x = f2bf(a.x) | (f2bf(a.y) << 16);
    w.y = f2bf(a.z) | (f2bf(a.w) << 16);
    w.z = f2bf(b.x) | (f2bf(b.y) << 16);
    w.w = f2bf(b.z) | (f2bf(b.w) << 16);
    ((uint4*)B16)[t] = w;
}

// ---------- per-step GNN: 8 active WGs (same XCD -> same L2), fixed small y buffers ----------
#define GATH(W) { float2 yy0 = y[(W) & 0xFFFFu]; a0 += yy0.x; a1 += yy0.y; \
                  float2 yy1 = y[(W) >> 16];     a0 += yy1.x; a1 += yy1.y; }

__global__ __launch_bounds__(512) void k_gnn(
    const float* __restrict__ vin, float* __restrict__ us,
    float2* __restrict__ ybuf, int* __restrict__ sb,
    const uint16_t* __restrict__ csr, const int* __restrict__ pad_ptr,
    const int* __restrict__ deg, const float* __restrict__ dinv,
    const float* __restrict__ rr,
    const float* __restrict__ W0, const float* __restrict__ b0,
    const float* __restrict__ Wh, const float* __restrict__ bh,
    const float* __restrict__ cst) {
    const int bid = blockIdx.x;
    if (bid & 7) return;                 // active: 0,8,..,56 -> one XCD under bid%8 round-robin
    __shared__ float2 y[NN + 1];         // y[n] = x[n]*dinv[n]; y[4096] = 0 sentinel
    const int g = bid >> 3;              // 0..7
    const int t = threadIdx.x;           // 0..511
    const int n = g * 512 + t;

    const float dv = dinv[n], rv = rr[n], dv2 = dv * dv;
    const int base = pad_ptr[n];
    const int nch = (deg[n] + 7) >> 3;
    const uint16_t* cp = csr + base;
    float dmy[8];
    #pragma unroll
    for (int j = 0; j < 8; ++j) dmy[j] = dinv[j * 512 + t];

    const float4 cc = *(const float4*)cst;   // precomputed layer-0 step constants

    float x0 = vin[n], x1 = vin[n + NN];
    #pragma unroll
    for (int j = 0; j < 8; ++j) {
        int mm = j * 512 + t;
        y[mm] = make_float2(vin[mm] * dmy[j], vin[mm + NN] * dmy[j]);
    }
    if (t == 0) y[NN] = make_float2(0.f, 0.f);
    __syncthreads();

    for (int l = 0; l < 8; ++l) {
        float wa00, wa01, wa10, wa11, wb00, wb01, wb10, wb11, bb0, bb1, e0, e1;
        if (l == 0) {
            wa00 = W0[0]; wa01 = W0[1]; wa10 = W0[2]; wa11 = W0[3];
            wb00 = W0[20]; wb01 = W0[21]; wb10 = W0[22]; wb11 = W0[23];
            bb0 = cc.x; bb1 = cc.y; e0 = cc.z; e1 = cc.w;
        } else {
            const float* wl = Wh + (l - 1) * 8;
            wa00 = wl[0]; wa01 = wl[1]; wa10 = wl[2]; wa11 = wl[3];
            wb00 = wl[4]; wb01 = wl[5]; wb10 = wl[6]; wb11 = wl[7];
            bb0 = bh[(l - 1) * 4 + 0] + bh[(l - 1) * 4 + 2];
            bb1 = bh[(l - 1) * 4 + 1] + bh[(l - 1) * 4 + 3];
            e0 = 0.f; e1 = 0.f;
        }

        float a0 = 0.f, a1 = 0.f;
        for (int c = 0; c < nch; ++c) {
            uint4 w = *(const uint4*)(cp + c * 8);
            GATH(w.x) GATH(w.y) GATH(w.z) GATH(w.w)
        }
        float P0 = dv * a0 + dv2 * x0;
        float P1 = dv * a1 + dv2 * x1;
        float o0 = x0 * wa00 + x1 * wa10 + P0 * wb00 + P1 * wb10 + bb0 + rv * e0;
        float o1 = x0 * wa01 + x1 * wa11 + P0 * wb01 + P1 * wb11 + bb1 + rv * e1;
        x0 = fmaxf(o0, 0.f);
        x1 = fmaxf(o1, 0.f);

        if (l < 7) {
            float2* yb = ybuf + (size_t)l * NN;    // fixed per-layer buffer (same-L2 reuse)
            int* fl = sb + l * 8;                  // 8 per-WG flags for this (step,layer)
            yb[n] = make_float2(x0 * dv, x1 * dv);
            __syncthreads();            // LDS reads done; yb stores vmcnt-drained (L2-ACKed)
            if (t == 0) flag_set(fl + g);          // relaxed flag: ordered by the drain above
            if (t < 64) {                          // wave 0: 8-lane parallel poll (L1-bypass)
                int it = 0;
                for (;;) {
                    int v = (t < 8) ? __hip_atomic_load(fl + t, __ATOMIC_RELAXED,
                                                        __HIP_MEMORY_SCOPE_AGENT) : 1;
                    if (__all(v != 0)) break;
                    __builtin_amdgcn_s_sleep(1);
                    if (++it > (1 << 22)) break;   // safety bail
                }
            }
            __syncthreads();
            asm volatile("" ::: "memory");
            const float4* src = (const float4*)yb;   // same-L2 hits
            float4* dst = (float4*)y;
            #pragma unroll
            for (int k = 0; k < 4; ++k) dst[k * 512 + t] = src[k * 512 + t];
            __syncthreads();
        }
    }

    us[n] = x0;
    us[n + NN] = x1;
    // launch boundary provides coherence to k_mv
}

// ---------- per-step matvec: vout = az + m@s + B16 @ u (permuted, conflict-free) ----------
__global__ __launch_bounds__(256) void k_mv(const uint16_t* __restrict__ B16,
                                            const float* __restrict__ u,
                                            const float* __restrict__ az,
                                            const float* __restrict__ m,
                                            const float* __restrict__ s,
                                            float* __restrict__ vout) {
    __shared__ float su[VD];
    int t = threadIdx.x;
    #pragma unroll
    for (int i = 0; i < 8; ++i) {
        int c = i * 1024 + t * 4;
        *(float4*)&su[c] = *(const float4*)&u[c];
    }
    __syncthreads();
    int wave = t >> 6, lane = t & 63;
    int r = blockIdx.x * 4 + wave;
    const uint4* bp = (const uint4*)(B16 + (size_t)r * VD);
    float acc = 0.f;
    #pragma unroll
    for (int jj = 0; jj < 16; ++jj) {
        uint4 w = bp[jj * 64 + lane];          // straight loads: compiler pipelines
        int c = jj * 512 + lane * 4;
        float4 ua = *(float4*)&su[c];          // contiguous 16B/lane: conflict-free
        float4 ub = *(float4*)&su[c + 256];
        acc += bfl(w.x) * ua.x + bfh(w.x) * ua.y + bfl(w.y) * ua.z + bfh(w.y) * ua.w
             + bfl(w.z) * ub.x + bfh(w.z) * ub.y + bfl(w.w) * ub.z + bfh(w.w) * ub.w;
    }
    for (int o = 32; o; o >>= 1) acc += __shfl_down(acc, o);
    if (lane == 0) {
        float cc = 0.f;
        #pragma unroll
        for (int k = 0; k < 8; ++k) cc += s[k] * m[r * 8 + k];
        vout[r] = az[r] + cc + acc;
    }
}

// ---------- launcher ----------
extern "C" void kernel_launch(void* const* d_in, const int* in_sizes, int n_in,
                              void* d_out, int out_size, void* d_ws, size_t ws_size,
                              hipStream_t stream) {
    const float* z   = (const float*)d_in[0];
    const int*   ei  = (const int*)d_in[1];
    const float* A_w = (const float*)d_in[2];
    const float* B_w = (const float*)d_in[3];
    const float* b_w = (const float*)d_in[4];
    const float* se  = (const float*)d_in[5];
    const float* gse = (const float*)d_in[6];
    const float* W0  = (const float*)d_in[7];
    const float* b0  = (const float*)d_in[8];
    const float* Wh  = (const float*)d_in[9];
    const float* bh  = (const float*)d_in[10];

    char* p = (char*)d_ws;
    auto carve = [&](size_t bytes) {
        void* r = (void*)p;
        p += (bytes + 255) & ~(size_t)255;
        return r;
    };
    uint16_t* B16    = (uint16_t*)carve((size_t)VD * VD * 2);
    float*    az     = (float*)carve(VD * 4);
    float*    m      = (float*)carve(VD * 8 * 4);
    float*    v0     = (float*)carve(VD * 4);
    float*    v1     = (float*)carve(VD * 4);
    float*    u      = (float*)carve(VD * 4);
    int*      deg    = (int*)carve(NN * 4);
    int*      fill   = (int*)carve(NN * 4);
    int*      padp   = (int*)carve(NN * 4);
    float*    rr     = (float*)carve(NN * 4);
    float*    dinv   = (float*)carve((NN + 1) * 4);
    uint16_t* csr    = (uint16_t*)carve(CSR_CAP * 2);
    float*    cbuf   = (float*)carve(NSTEPS * 4 * 4);        // per-step layer-0 constants
    float2*   ybuf   = (float2*)carve((size_t)7 * NN * 8);   // 7 fixed exchange buffers (224 KB)
    int*      bar    = (int*)carve((size_t)BARN * 4);        // monotonic flags (25.6 KB)

    k_zero<<<CSR_CAP / 2 / 256, 256, 0, stream>>>(deg, fill, v0, (uint32_t*)csr, bar);
    k_deg<<<NE / 256, 256, 0, stream>>>(ei, deg);
    k_scan<<<1, 1024, 0, stream>>>(deg, padp, dinv);
    k_fill<<<NE / 256, 256, 0, stream>>>(ei, padp, fill, csr);
    k_r<<<NN / 256, 256, 0, stream>>>(deg, padp, csr, dinv, rr);
    k_m<<<VD * 8 / 256, 256, 0, stream>>>(A_w, B_w, b_w, m);
    k_c<<<2, 64, 0, stream>>>(W0, b0, gse, cbuf);
    k_az<<<VD / 4, 256, 0, stream>>>(A_w, z, az);
    k_bconv<<<VD * 1024 / 256, 256, 0, stream>>>(B_w, B16);

    const float* vin = v0;
    for (int t = 0; t < NSTEPS; ++t) {
        float* vout = (t == NSTEPS - 1) ? (float*)d_out : ((t & 1) ? v0 : v1);
        k_gnn<<<64, 512, 0, stream>>>(vin, u, ybuf, bar + t * SSTR,
                                      csr, padp, deg, dinv, rr,
                                      W0, b0, Wh, bh, cbuf + 4 * t);
        k_mv<<<VD / 4, 256, 0, stream>>>(B16, u, az, m, se + 8 * t, vout);
        vin = vout;
    }
}

// Round 16
// 4472.317 us; speedup vs baseline: 3.1894x; 1.0072x over previous
//
#include <hip/hip_runtime.h>
#include <stdint.h>

#define NN 4096
#define VD 8192
#define NE 65536
#define NSTEPS 100
#define CSR_CAP 98304  // 65536 + worst-case per-node pad (<= 7*4096) rounded up

#define GWG 8          // GNN workgroups (active bids 0,8,...,56 of a 64-block launch)
#define SSTR 64        // flag ints per step (l*8+g for l=0..6, g=0..7)
#define BARN (NSTEPS * SSTR)

// ---------- helpers ----------
__device__ __forceinline__ uint32_t f2bf(float f) {
    uint32_t x = __float_as_uint(f);
    return (x + 0x7FFFu + ((x >> 16) & 1u)) >> 16;
}
__device__ __forceinline__ float bfl(uint32_t w) { return __uint_as_float(w << 16); }
__device__ __forceinline__ float bfh(uint32_t w) { return __uint_as_float(w & 0xFFFF0000u); }

__device__ __forceinline__ void flag_set(int* f) {
    // RELAXED, not release: data stores are already L2-ACKed (vmcnt(0) drained by the
    // preceding __syncthreads), and producer+consumer share one XCD L2 (bid placement).
    // Release's wbl2+wait cost ~1us on the exchange critical path (R15 measurement).
    __hip_atomic_store(f, 1, __ATOMIC_RELAXED, __HIP_MEMORY_SCOPE_AGENT);
}

// ---------- setup kernels ----------
__global__ void k_zero(int* deg, int* fill, float* v0, uint32_t* csrw, int* bar) {
    int t = blockIdx.x * 256 + threadIdx.x;           // grid covers 49152
    if (t < 4096) { deg[t] = 0; fill[t] = 0; }
    if (t < 8192) v0[t] = 0.f;
    if (t < BARN) bar[t] = 0;                         // monotonic flags, zeroed per replay
    if (t < CSR_CAP / 2) csrw[t] = 0x10001000u;       // sentinel src = 4096
}

__global__ void k_deg(const int* ei, int* deg) {
    int e = blockIdx.x * 256 + threadIdx.x;
    if (e < NE) atomicAdd(&deg[ei[NE + e]], 1);
}

__global__ __launch_bounds__(1024) void k_scan(const int* deg, int* pad_ptr, float* dinv) {
    __shared__ int sh[1024];
    int t = threadIdx.x;
    int d[4], pl[4], tsum = 0;
    for (int j = 0; j < 4; ++j) {
        d[j] = deg[t * 4 + j];
        pl[j] = (d[j] + 7) & ~7;
        tsum += pl[j];
    }
    sh[t] = tsum;
    __syncthreads();
    for (int off = 1; off < 1024; off <<= 1) {
        int v = sh[t];
        if (t >= off) v += sh[t - off];
        __syncthreads();
        sh[t] = v;
        __syncthreads();
    }
    int base = sh[t] - tsum;  // exclusive prefix
    for (int j = 0; j < 4; ++j) {
        pad_ptr[t * 4 + j] = base;
        base += pl[j];
        dinv[t * 4 + j] = rsqrtf((float)(d[j] + 1));  // +1 self loop, always > 0
    }
    if (t == 0) dinv[4096] = 0.f;  // sentinel
}

__global__ void k_fill(const int* ei, const int* pad_ptr, int* fill, uint16_t* csr) {
    int e = blockIdx.x * 256 + threadIdx.x;
    if (e < NE) {
        int s = ei[e];
        int d = ei[NE + e];
        int pos = atomicAdd(&fill[d], 1);
        csr[pad_ptr[d] + pos] = (uint16_t)s;
    }
}

__global__ void k_r(const int* deg, const int* pad_ptr, const uint16_t* csr,
                    const float* dinv, float* rr) {
    int n = blockIdx.x * 256 + threadIdx.x;
    if (n >= NN) return;
    float dv = dinv[n];
    int base = pad_ptr[n];
    int nch = (deg[n] + 7) >> 3;
    float sum = 0.f;
    for (int c = 0; c < nch; ++c)
        for (int k = 0; k < 8; ++k) sum += dinv[csr[base + c * 8 + k]];  // sentinel adds 0
    rr[n] = dv * sum + dv * dv;
}

__global__ void k_m(const float* A, const float* B, const float* bw, float* m) {
    int t = blockIdx.x * 256 + threadIdx.x;  // 65536
    if (t >= VD * 8) return;
    int i = t >> 3, k = t & 7;
    m[t] = A[(size_t)i * 8200 + 8192 + k] + B[(size_t)i * 8200 + 8192 + k] + bw[i * 8 + k];
}

// per-step layer-0 constants, precomputed once (hoisted out of k_gnn's prologue)
__global__ void k_c(const float* W0, const float* b0, const float* gse, float* cbuf) {
    int s = blockIdx.x * 64 + threadIdx.x;
    if (s >= NSTEPS) return;
    const float* gs = gse + 8 * s;
    float c0_0 = b0[0] + b0[2], c0_1 = b0[1] + b0[3];
    float c1_0 = 0.f, c1_1 = 0.f;
    for (int k = 0; k < 8; ++k) {
        float sv = gs[k];
        c0_0 += sv * W0[(2 + k) * 2 + 0];
        c0_1 += sv * W0[(2 + k) * 2 + 1];
        c1_0 += sv * W0[20 + (2 + k) * 2 + 0];
        c1_1 += sv * W0[20 + (2 + k) * 2 + 1];
    }
    ((float4*)cbuf)[s] = make_float4(c0_0, c0_1, c1_0, c1_1);
}

__global__ __launch_bounds__(256) void k_az(const float* A, const float* z, float* az) {
    int wave = threadIdx.x >> 6, lane = threadIdx.x & 63;
    int r = blockIdx.x * 4 + wave;
    const float* row = A + (size_t)r * 8200;
    float acc = 0.f;
    for (int j = 0; j < 32; ++j) {
        int c = j * 256 + lane * 4;
        float4 a = *(const float4*)(row + c);
        float4 zz = *(const float4*)(z + c);
        acc += a.x * zz.x + a.y * zz.y + a.z * zz.z + a.w * zz.w;
    }
    for (int o = 32; o; o >>= 1) acc += __shfl_down(acc, o);
    if (lane == 0) az[r] = acc;
}

// Permuted B16 layout: row r, uint4 index p = jj*64 + l holds bf16 of cols
// {jj*512+4l .. +3} (words x,y) and {jj*512+256+4l .. +3} (words z,w).
// This makes the mv-phase su reads contiguous 16B/lane -> conflict-free LDS.
__global__ __launch_bounds__(256) void k_bconv(const float* B, uint16_t* B16) {
    int t = blockIdx.x * 256 + threadIdx.x;  // VD*1024 threads, one uint4 each
    int i = t >> 10;
    int p = t & 1023;
    int jj = p >> 6, l = p & 63;
    const float* pr = B + (size_t)i * 8200 + jj * 512 + l * 4;
    float4 a = *(const float4*)pr;
    float4 b = *(const float4*)(pr + 256);
    uint4 w;
    w.x = f2bf(a.x) | (f2bf(a.y) << 16);
    w.y = f2bf(a.z) | (f2bf(a.w) << 16);
    w.z = f2bf(b.x) | (f2bf(b.y) << 16);
    w.w = f2bf(b.z) | (f2bf(b.w) << 16);
    ((uint4*)B16)[t] = w;
}

// ---------- per-step GNN: 8 active WGs (same XCD -> same L2), fixed small y buffers ----------
#define GATH(W) { float2 yy0 = y[(W) & 0xFFFFu]; a0 += yy0.x; a1 += yy0.y; \
                  float2 yy1 = y[(W) >> 16];     a0 += yy1.x; a1 += yy1.y; }

__global__ __launch_bounds__(512) void k_gnn(
    const float* __restrict__ vin, float* __restrict__ us,
    float2* __restrict__ ybuf, int* __restrict__ sb,
    const uint16_t* __restrict__ csr, const int* __restrict__ pad_ptr,
    const int* __restrict__ deg, const float* __restrict__ dinv,
    const float* __restrict__ rr,
    const float* __restrict__ W0, const float* __restrict__ b0,
    const float* __restrict__ Wh, const float* __restrict__ bh,
    const float* __restrict__ cst) {
    const int bid = blockIdx.x;
    if (bid & 7) return;                 // active: 0,8,..,56 -> one XCD under bid%8 round-robin
    __shared__ float2 y[NN + 1];         // y[n] = x[n]*dinv[n]; y[4096] = 0 sentinel
    const int g = bid >> 3;              // 0..7
    const int t = threadIdx.x;           // 0..511
    const int n = g * 512 + t;

    const float dv = dinv[n], rv = rr[n], dv2 = dv * dv;
    const int base = pad_ptr[n];
    const int nch = (deg[n] + 7) >> 3;
    const uint16_t* cp = csr + base;
    float dmy[8];
    #pragma unroll
    for (int j = 0; j < 8; ++j) dmy[j] = dinv[j * 512 + t];

    const float4 cc = *(const float4*)cst;   // precomputed layer-0 step constants

    float x0 = vin[n], x1 = vin[n + NN];
    #pragma unroll
    for (int j = 0; j < 8; ++j) {
        int mm = j * 512 + t;
        y[mm] = make_float2(vin[mm] * dmy[j], vin[mm + NN] * dmy[j]);
    }
    if (t == 0) y[NN] = make_float2(0.f, 0.f);
    __syncthreads();

    for (int l = 0; l < 8; ++l) {
        float wa00, wa01, wa10, wa11, wb00, wb01, wb10, wb11, bb0, bb1, e0, e1;
        if (l == 0) {
            wa00 = W0[0]; wa01 = W0[1]; wa10 = W0[2]; wa11 = W0[3];
            wb00 = W0[20]; wb01 = W0[21]; wb10 = W0[22]; wb11 = W0[23];
            bb0 = cc.x; bb1 = cc.y; e0 = cc.z; e1 = cc.w;
        } else {
            const float* wl = Wh + (l - 1) * 8;
            wa00 = wl[0]; wa01 = wl[1]; wa10 = wl[2]; wa11 = wl[3];
            wb00 = wl[4]; wb01 = wl[5]; wb10 = wl[6]; wb11 = wl[7];
            bb0 = bh[(l - 1) * 4 + 0] + bh[(l - 1) * 4 + 2];
            bb1 = bh[(l - 1) * 4 + 1] + bh[(l - 1) * 4 + 3];
            e0 = 0.f; e1 = 0.f;
        }

        float a0 = 0.f, a1 = 0.f;
        for (int c = 0; c < nch; ++c) {
            uint4 w = *(const uint4*)(cp + c * 8);
            GATH(w.x) GATH(w.y) GATH(w.z) GATH(w.w)
        }
        float P0 = dv * a0 + dv2 * x0;
        float P1 = dv * a1 + dv2 * x1;
        float o0 = x0 * wa00 + x1 * wa10 + P0 * wb00 + P1 * wb10 + bb0 + rv * e0;
        float o1 = x0 * wa01 + x1 * wa11 + P0 * wb01 + P1 * wb11 + bb1 + rv * e1;
        x0 = fmaxf(o0, 0.f);
        x1 = fmaxf(o1, 0.f);

        if (l < 7) {
            float2* yb = ybuf + (size_t)l * NN;    // fixed per-layer buffer (same-L2 reuse)
            int* fl = sb + l * 8;                  // 8 per-WG flags for this (step,layer)
            yb[n] = make_float2(x0 * dv, x1 * dv);
            __syncthreads();            // LDS reads done; yb stores vmcnt-drained (L2-ACKed)
            if (t == 0) flag_set(fl + g);          // relaxed flag: ordered by the drain above
            if (t < 64) {                          // wave 0: 8-lane parallel poll (L1-bypass)
                int it = 0;
                for (;;) {
                    int v = (t < 8) ? __hip_atomic_load(fl + t, __ATOMIC_RELAXED,
                                                        __HIP_MEMORY_SCOPE_AGENT) : 1;
                    if (__all(v != 0)) break;
                    __builtin_amdgcn_s_sleep(1);
                    if (++it > (1 << 22)) break;   // safety bail
                }
            }
            __syncthreads();
            asm volatile("" ::: "memory");
            const float4* src = (const float4*)yb;   // same-L2 hits
            float4* dst = (float4*)y;
            #pragma unroll
            for (int k = 0; k < 4; ++k) dst[k * 512 + t] = src[k * 512 + t];
            __syncthreads();
        }
    }

    us[n] = x0;
    us[n + NN] = x1;
    // launch boundary provides coherence to k_mv
}

// ---------- per-step matvec: vout = az + m@s + B16 @ u (permuted, conflict-free) ----------
// 1024 blocks x 512 thr (8 waves): 8 rows/block, ONE row per wave (row parallelism
// unchanged at 8192 waves); u broadcast halves 64->32 MB/step.
__global__ __launch_bounds__(512) void k_mv(const uint16_t* __restrict__ B16,
                                            const float* __restrict__ u,
                                            const float* __restrict__ az,
                                            const float* __restrict__ m,
                                            const float* __restrict__ s,
                                            float* __restrict__ vout) {
    __shared__ float su[VD];
    int t = threadIdx.x;
    #pragma unroll
    for (int i = 0; i < 4; ++i) {
        int c = i * 2048 + t * 4;
        *(float4*)&su[c] = *(const float4*)&u[c];
    }
    __syncthreads();
    int wave = t >> 6, lane = t & 63;
    int r = blockIdx.x * 8 + wave;
    const uint4* bp = (const uint4*)(B16 + (size_t)r * VD);
    float acc = 0.f;
    #pragma unroll
    for (int jj = 0; jj < 16; ++jj) {
        uint4 w = bp[jj * 64 + lane];          // straight loads: compiler pipelines
        int c = jj * 512 + lane * 4;
        float4 ua = *(float4*)&su[c];          // contiguous 16B/lane: conflict-free
        float4 ub = *(float4*)&su[c + 256];
        acc += bfl(w.x) * ua.x + bfh(w.x) * ua.y + bfl(w.y) * ua.z + bfh(w.y) * ua.w
             + bfl(w.z) * ub.x + bfh(w.z) * ub.y + bfl(w.w) * ub.z + bfh(w.w) * ub.w;
    }
    for (int o = 32; o; o >>= 1) acc += __shfl_down(acc, o);
    if (lane == 0) {
        float cc = 0.f;
        #pragma unroll
        for (int k = 0; k < 8; ++k) cc += s[k] * m[r * 8 + k];
        vout[r] = az[r] + cc + acc;
    }
}

// ---------- launcher ----------
extern "C" void kernel_launch(void* const* d_in, const int* in_sizes, int n_in,
                              void* d_out, int out_size, void* d_ws, size_t ws_size,
                              hipStream_t stream) {
    const float* z   = (const float*)d_in[0];
    const int*   ei  = (const int*)d_in[1];
    const float* A_w = (const float*)d_in[2];
    const float* B_w = (const float*)d_in[3];
    const float* b_w = (const float*)d_in[4];
    const float* se  = (const float*)d_in[5];
    const float* gse = (const float*)d_in[6];
    const float* W0  = (const float*)d_in[7];
    const float* b0  = (const float*)d_in[8];
    const float* Wh  = (const float*)d_in[9];
    const float* bh  = (const float*)d_in[10];

    char* p = (char*)d_ws;
    auto carve = [&](size_t bytes) {
        void* r = (void*)p;
        p += (bytes + 255) & ~(size_t)255;
        return r;
    };
    uint16_t* B16    = (uint16_t*)carve((size_t)VD * VD * 2);
    float*    az     = (float*)carve(VD * 4);
    float*    m      = (float*)carve(VD * 8 * 4);
    float*    v0     = (float*)carve(VD * 4);
    float*    v1     = (float*)carve(VD * 4);
    float*    u      = (float*)carve(VD * 4);
    int*      deg    = (int*)carve(NN * 4);
    int*      fill   = (int*)carve(NN * 4);
    int*      padp   = (int*)carve(NN * 4);
    float*    rr     = (float*)carve(NN * 4);
    float*    dinv   = (float*)carve((NN + 1) * 4);
    uint16_t* csr    = (uint16_t*)carve(CSR_CAP * 2);
    float*    cbuf   = (float*)carve(NSTEPS * 4 * 4);        // per-step layer-0 constants
    float2*   ybuf   = (float2*)carve((size_t)7 * NN * 8);   // 7 fixed exchange buffers (224 KB)
    int*      bar    = (int*)carve((size_t)BARN * 4);        // monotonic flags (25.6 KB)

    k_zero<<<CSR_CAP / 2 / 256, 256, 0, stream>>>(deg, fill, v0, (uint32_t*)csr, bar);
    k_deg<<<NE / 256, 256, 0, stream>>>(ei, deg);
    k_scan<<<1, 1024, 0, stream>>>(deg, padp, dinv);
    k_fill<<<NE / 256, 256, 0, stream>>>(ei, padp, fill, csr);
    k_r<<<NN / 256, 256, 0, stream>>>(deg, padp, csr, dinv, rr);
    k_m<<<VD * 8 / 256, 256, 0, stream>>>(A_w, B_w, b_w, m);
    k_c<<<2, 64, 0, stream>>>(W0, b0, gse, cbuf);
    k_az<<<VD / 4, 256, 0, stream>>>(A_w, z, az);
    k_bconv<<<VD * 1024 / 256, 256, 0, stream>>>(B_w, B16);

    const float* vin = v0;
    for (int t = 0; t < NSTEPS; ++t) {
        float* vout = (t == NSTEPS - 1) ? (float*)d_out : ((t & 1) ? v0 : v1);
        k_gnn<<<64, 512, 0, stream>>>(vin, u, ybuf, bar + t * SSTR,
                                      csr, padp, deg, dinv, rr,
                                      W0, b0, Wh, bh, cbuf + 4 * t);
        k_mv<<<VD / 8, 512, 0, stream>>>(B16, u, az, m, se + 8 * t, vout);
        vin = vout;
    }
}